// Round 21
// baseline (166.281 us; speedup 1.0000x reference)
//
#include <hip/hip_runtime.h>

#define HH 4
#define CC 128
#define NPB 64

typedef __attribute__((ext_vector_type(8))) short short8v;   // 8 bf16
typedef __attribute__((ext_vector_type(4))) float f32x4;

static inline size_t roundup256(size_t x) { return (x + 255) & ~(size_t)255; }

static __device__ __forceinline__ unsigned short f2bf(float f) {
    unsigned int u = __float_as_uint(f);
    unsigned int r = (u + 0x7FFFu + ((u >> 16) & 1u)) >> 16;   // RNE
    return (unsigned short)r;
}

// ---------------- prep: mean + hist + Lin + packed (f32) + pwB --------------
__global__ __launch_bounds__(256) void prep_kernel(
    const int* __restrict__ ei, const float* __restrict__ eattr,
    float* __restrict__ meansum, float* __restrict__ Lin, int* __restrict__ cnt,
    const float* __restrict__ Wsrc0, const float* __restrict__ bsrc0,
    const float* __restrict__ Wdst0, const float* __restrict__ bdst0,
    const float* __restrict__ Wedge0, const float* __restrict__ att0,
    const float* __restrict__ Wsrc1, const float* __restrict__ bsrc1,
    const float* __restrict__ Wdst1, const float* __restrict__ bdst1,
    const float* __restrict__ Wedge1, const float* __restrict__ att1,
    const float* __restrict__ Wfuse,
    float* __restrict__ packed, unsigned short* __restrict__ pwB, int E)
{
    int tid = blockIdx.x * 256 + threadIdx.x;
    int lane = threadIdx.x & 63, wid = threadIdx.x >> 6;
    float s = 0.f;
    if (tid < E) {
        atomicAdd(&cnt[ei[E + tid]], 1);
        s = eattr[tid];
    }
    #pragma unroll
    for (int off = 32; off > 0; off >>= 1) s += __shfl_down(s, off, 64);
    __shared__ float wsum[4];
    if (lane == 0) wsum[wid] = s;
    __syncthreads();
    if (threadIdx.x == 0)
        atomicAdd(meansum, wsum[0] + wsum[1] + wsum[2] + wsum[3]);

    if (blockIdx.x < 4) {  // tid < 1024: one thread per (b,h,c)
        int b = tid >> 9;
        int hc = tid & 511;
        int c = hc & 127;
        int h = hc >> 7;
        int bh = b * 4 + h;
        const float* Ws = b ? Wsrc1 : Wsrc0;
        const float* bs = b ? bsrc1 : bsrc0;
        const float* Wd = b ? Wdst1 : Wdst0;
        const float* bd = b ? bdst1 : bdst0;
        const float* We = b ? Wedge1 : Wedge0;
        const float* at = b ? att1 : att0;
        float A = Ws[hc], B = Ws[512 + hc];
        float C = Wd[hc], D = Wd[512 + hc];
        float Ec = We[hc];
        float F = bs[hc] + bd[hc];
        float a = at[hc];
        float4* r = (float4*)(packed + ((size_t)(bh * 128 + c)) * 8);
        r[0] = make_float4(A, B, C, D);
        r[1] = make_float4(Ec, F, 0.4f * a, 0.f);
        float sa = 0.6f * a;
        float vals[6] = {sa * A, sa * B, sa * C, sa * D, sa * Ec, sa * F};
        #pragma unroll
        for (int k = 0; k < 6; ++k) {
            float v = vals[k];
            #pragma unroll
            for (int off = 32; off > 0; off >>= 1) v += __shfl_down(v, off, 64);
            vals[k] = v;
        }
        __shared__ float Ls[4][6];
        if (lane == 0) {
            #pragma unroll
            for (int k = 0; k < 6; ++k) Ls[wid][k] = vals[k];
        }
        __syncthreads();
        if (threadIdx.x < 12) {
            int w2 = threadIdx.x / 6;
            int k = threadIdx.x % 6;
            int bhg = blockIdx.x * 2 + w2;
            Lin[bhg * 6 + k] = Ls[w2 * 2][k] + Ls[w2 * 2 + 1][k];
        }
    }

    if (blockIdx.x >= 4 && blockIdx.x < 20) {  // Wfuse -> bf16 B-frags (node)
        int t2 = tid - 1024;                   // 0..4095
        int ct = t2 >> 9;
        int kc = (t2 >> 6) & 7;
        int l  = t2 & 63;
        int c = ct * 16 + (l & 15);
        int kb = kc * 32 + (l >> 4) * 8;
        unsigned short v[8];
        #pragma unroll
        for (int j = 0; j < 8; ++j)
            v[j] = f2bf(Wfuse[(kb + j) * CC + c]);
        unsigned short* dst = pwB + (size_t)t2 * 8;
        #pragma unroll
        for (int j = 0; j < 8; ++j) dst[j] = v[j];
    }
}

// ---------------- scan: shuffle-based exclusive prefix over (cnt+1) ---------
__global__ __launch_bounds__(1024) void scan_kernel(const int* __restrict__ cnt,
                                                    int* __restrict__ rowptr,
                                                    int* __restrict__ cur, int N) {
    const int CH = 32;
    int t = threadIdx.x;
    int lane = t & 63, wid = t >> 6;
    int base = t * CH;
    int local[CH];
    int own = 0;
    #pragma unroll
    for (int i = 0; i < CH; ++i) {
        int idx = base + i;
        int v = (idx < N) ? cnt[idx] + 1 : 0;  // +1 = self loop
        local[i] = own;
        own += v;
    }
    int incl = own;
    #pragma unroll
    for (int off = 1; off < 64; off <<= 1) {
        int v = __shfl_up(incl, off, 64);
        if (lane >= off) incl += v;
    }
    __shared__ int wtot[16];
    __shared__ int wexcl[17];
    if (lane == 63) wtot[wid] = incl;
    __syncthreads();
    if (t == 0) {
        int acc = 0;
        #pragma unroll
        for (int w = 0; w < 16; ++w) { wexcl[w] = acc; acc += wtot[w]; }
        wexcl[16] = acc;
    }
    __syncthreads();
    int excl = wexcl[wid] + (incl - own);
    #pragma unroll
    for (int i = 0; i < CH; ++i) {
        int idx = base + i;
        if (idx < N) {
            int v = excl + local[i];
            rowptr[idx] = v;
            cur[idx] = v;
        }
    }
    if (t == 1023) rowptr[N] = wexcl[16];
}

// ---------------- scatter: CSR records ed4{xs,xd}, ea1, esrc ----------------
__global__ __launch_bounds__(256) void scatter_kernel(
    const int* __restrict__ ei, const float* __restrict__ x,
    const float* __restrict__ eattr, const float* __restrict__ meansum,
    int* __restrict__ cur, float4* __restrict__ ed4, float* __restrict__ ea1,
    int* __restrict__ esrc, int N, int E) {
    int e = blockIdx.x * 256 + threadIdx.x;
    int Etot = E + N;
    if (e >= Etot) return;
    int src, dst;
    float ea;
    if (e < E) { src = ei[e]; dst = ei[E + e]; ea = eattr[e]; }
    else       { src = e - E; dst = src; ea = meansum[0] / (float)E; }
    int pos = atomicAdd(&cur[dst], 1);
    const float2* x2 = (const float2*)x;
    float2 xs = x2[src];
    float2 xd = x2[dst];
    ed4[pos] = make_float4(xs.x, xs.y, xd.x, xd.y);
    ea1[pos] = ea;
    esrc[pos] = src;
}

// ---------------- logits: 2 bh per block (scalar), 2 edges/lane -------------
// grid = 4 bh-pair-phases x nchunks; each block: 2 bh, 512 edges (2/lane).
// Edge data loaded once, used for both bh -> halved fetch traffic.
__global__ __launch_bounds__(256) void logits_kernel(
    const float4* __restrict__ ed4,
    const float* __restrict__ ea1,
    const float* __restrict__ Lin,
    const float4* __restrict__ pw,   // (bh*128+c)*2 float4: {A,B,C,D},{E,F,G',0}
    float* __restrict__ p8, int EtotPad, int nchunks)
{
    int blk = blockIdx.x;
    int bhp = blk / nchunks;         // 0..3 (bh pair), phase-major sweep
    int chunk = blk - bhp * nchunks;
    int t = threadIdx.x;
    int iA = chunk * 512 + t;
    int iB = iA + 256;
    float4 eA = ed4[iA], eB = ed4[iB];
    float aA = ea1[iA], aB = ea1[iB];

    #pragma unroll
    for (int bi = 0; bi < 2; ++bi) {
        int bh = bhp * 2 + bi;
        const float4* wp = pw + (size_t)bh * 256;   // 4KB slice, scalar-L1 hot
        float a0 = 0.f, a1 = 0.f;
        #pragma unroll 8
        for (int c = 0; c < 128; ++c) {
            float4 w0 = wp[2 * c];       // uniform -> s_load, K$ hit
            float4 w1 = wp[2 * c + 1];
            float uA = fmaf(w0.x, eA.x,
                       fmaf(w0.y, eA.y,
                       fmaf(w0.z, eA.z,
                       fmaf(w0.w, eA.w,
                       fmaf(w1.x, aA, w1.y)))));
            float uB = fmaf(w0.x, eB.x,
                       fmaf(w0.y, eB.y,
                       fmaf(w0.z, eB.z,
                       fmaf(w0.w, eB.w,
                       fmaf(w1.x, aB, w1.y)))));
            a0 = fmaf(w1.z, __builtin_fabsf(uA), a0);  // |u| = free src modifier
            a1 = fmaf(w1.z, __builtin_fabsf(uB), a1);
        }
        const float* Lp = Lin + bh * 6;   // uniform -> s_load
        float lgA = fmaf(Lp[0], eA.x, fmaf(Lp[1], eA.y, fmaf(Lp[2], eA.z,
                    fmaf(Lp[3], eA.w, fmaf(Lp[4], aA, Lp[5]))))) + a0;
        float lgB = fmaf(Lp[0], eB.x, fmaf(Lp[1], eB.y, fmaf(Lp[2], eB.z,
                    fmaf(Lp[3], eB.w, fmaf(Lp[4], aB, Lp[5]))))) + a1;
        float* plane = p8 + (size_t)bh * EtotPad;
        plane[iA] = __expf(lgA);
        plane[iB] = __expf(lgB);
    }
}

// ---------------- node: gather (fused) + h-build + MFMA fuse GEMM -----------
// phase0: 16 lanes/node (8 bh x 2 edge-parity), shfl_xor(8) combine, 2 passes
__global__ __launch_bounds__(512) void node_kernel(
    const float* __restrict__ x,
    const int* __restrict__ rowptr,
    const int* __restrict__ esrc,
    const float* __restrict__ p8,
    const float* __restrict__ Wsrc0, const float* __restrict__ bsrc0,
    const float* __restrict__ bias0, const float* __restrict__ Wres0,
    const float* __restrict__ Wsrc1, const float* __restrict__ bsrc1,
    const float* __restrict__ bias1, const float* __restrict__ Wres1,
    const unsigned short* __restrict__ pwB, const float* __restrict__ bfuse,
    float* __restrict__ out, int N, int EtotPad)
{
    __shared__ __align__(16) unsigned short hb[NPB][264];  // 33 KB
    __shared__ __align__(16) float Sl[NPB][24];            // 6 KB
    int t = threadIdx.x;
    int n0 = blockIdx.x * NPB;
    const float2* x2 = (const float2*)x;

    // ---- phase 0: per-node gather, 16 lanes/node, two passes ----
    {
        int g = t >> 4;            // 0..31 node in pass
        int sub = t & 15;
        int bh = sub & 7;
        int half = sub >> 3;       // edge parity
        const float* plane = p8 + (size_t)bh * EtotPad;
        #pragma unroll
        for (int pass = 0; pass < 2; ++pass) {
            int ni = g + pass * 32;
            int n = n0 + ni;
            if (n < N) {
                int beg = rowptr[n], end = rowptr[n + 1];
                float s0 = 0.f, s1 = 0.f, sb = 0.f;
                for (int i = beg + half; i < end; i += 2) {
                    float p = plane[i];
                    int srcu = esrc[i];
                    float2 xs = x2[srcu];       // L2-hot gather
                    s0 = fmaf(p, xs.x, s0);
                    s1 = fmaf(p, xs.y, s1);
                    sb += p;
                }
                s0 += __shfl_xor(s0, 8, 64);
                s1 += __shfl_xor(s1, 8, 64);
                sb += __shfl_xor(sb, 8, 64);
                if (half == 0) {
                    float rin = 1.f / (sb + 1e-16f);
                    Sl[ni][bh * 3 + 0] = s0 * rin;
                    Sl[ni][bh * 3 + 1] = s1 * rin;
                    Sl[ni][bh * 3 + 2] = sb * rin;
                }
            }
        }
    }
    __syncthreads();

    // ---- phase 1: h build ----
    int c = t & (CC - 1);
    int quarter = t >> 7;

    float w00[HH], w01[HH], wb0[HH], w10[HH], w11[HH], wb1[HH];
    #pragma unroll
    for (int h = 0; h < HH; ++h) {
        w00[h] = Wsrc0[h * CC + c];
        w01[h] = Wsrc0[512 + h * CC + c];
        wb0[h] = bsrc0[h * CC + c];
        w10[h] = Wsrc1[h * CC + c];
        w11[h] = Wsrc1[512 + h * CC + c];
        wb1[h] = bsrc1[h * CC + c];
    }
    float bi0 = bias0[c], bi1 = bias1[c];
    float r00 = Wres0[c], r01 = Wres0[CC + c];
    float r10 = Wres1[c], r11 = Wres1[CC + c];

    for (int ni = quarter; ni < NPB; ni += 4) {
        int n = n0 + ni;
        if (n < N) {
            float x0 = x[2 * n], x1 = x[2 * n + 1];
            const float4* Sp4 = (const float4*)&Sl[ni][0];  // LDS broadcast
            float4 q0 = Sp4[0], q1 = Sp4[1], q2 = Sp4[2];
            float4 q3 = Sp4[3], q4 = Sp4[4], q5 = Sp4[5];
            float h0v, h1v;
            {
                float s0[HH] = {q0.x, q0.w, q1.z, q2.y};
                float s1[HH] = {q0.y, q1.x, q1.w, q2.z};
                float sb[HH] = {q0.z, q1.y, q2.x, q2.w};
                float acc = 0.f;
                #pragma unroll
                for (int h = 0; h < HH; ++h)
                    acc += fmaf(w00[h], s0[h], fmaf(w01[h], s1[h], wb0[h] * sb[h]));
                float o = fmaxf(acc * 0.25f + bi0, 0.f);
                h0v = o + x0 * r00 + x1 * r01;
            }
            {
                float s0[HH] = {q3.x, q3.w, q4.z, q5.y};
                float s1[HH] = {q3.y, q4.x, q4.w, q5.z};
                float sb[HH] = {q3.z, q4.y, q5.x, q5.w};
                float acc = 0.f;
                #pragma unroll
                for (int h = 0; h < HH; ++h)
                    acc += fmaf(w10[h], s0[h], fmaf(w11[h], s1[h], wb1[h] * sb[h]));
                float o = fmaxf(acc * 0.25f + bi1, 0.f);
                h1v = o + x0 * r10 + x1 * r11;
            }
            hb[ni][c] = f2bf(h0v);
            hb[ni][CC + c] = f2bf(h1v);
        }
    }
    __syncthreads();

    // ---- phase 2: MFMA ----
    int w = t >> 6;
    int l = t & 63;
    int nt = w & 3;
    int cthalf = w >> 2;
    int row = nt * 16 + (l & 15);

    short8v a[8];
    #pragma unroll
    for (int kc = 0; kc < 8; ++kc)
        a[kc] = *reinterpret_cast<const short8v*>(&hb[row][kc * 32 + (l >> 4) * 8]);

    const short8v* pB = reinterpret_cast<const short8v*>(pwB);
    #pragma unroll
    for (int ci = 0; ci < 4; ++ci) {
        int ct = cthalf * 4 + ci;
        f32x4 acc = {0.f, 0.f, 0.f, 0.f};
        #pragma unroll
        for (int kc = 0; kc < 8; ++kc) {
            short8v b = pB[(ct * 8 + kc) * 64 + l];
            acc = __builtin_amdgcn_mfma_f32_16x16x32_bf16(a[kc], b, acc, 0, 0, 0);
        }
        int ch = ct * 16 + (l & 15);
        float bi = bfuse[ch];
        #pragma unroll
        for (int j = 0; j < 4; ++j) {
            int n = n0 + nt * 16 + (l >> 4) * 4 + j;
            if (n < N) out[(size_t)n * CC + ch] = fmaxf(acc[j] + bi, 0.f);
        }
    }
}

extern "C" void kernel_launch(void* const* d_in, const int* in_sizes, int n_in,
                              void* d_out, int out_size, void* d_ws, size_t ws_size,
                              hipStream_t stream) {
    const float* x      = (const float*)d_in[0];
    const int*   ei     = (const int*)d_in[1];
    const float* eattr  = (const float*)d_in[2];
    const float* Wsrc0  = (const float*)d_in[3];
    const float* bsrc0  = (const float*)d_in[4];
    const float* Wdst0  = (const float*)d_in[5];
    const float* bdst0  = (const float*)d_in[6];
    const float* Wedge0 = (const float*)d_in[7];
    const float* att0   = (const float*)d_in[8];
    const float* bias0  = (const float*)d_in[9];
    const float* Wres0  = (const float*)d_in[10];
    const float* Wsrc1  = (const float*)d_in[11];
    const float* bsrc1  = (const float*)d_in[12];
    const float* Wdst1  = (const float*)d_in[13];
    const float* bdst1  = (const float*)d_in[14];
    const float* Wedge1 = (const float*)d_in[15];
    const float* att1   = (const float*)d_in[16];
    const float* bias1  = (const float*)d_in[17];
    const float* Wres1  = (const float*)d_in[18];
    const float* Wfuse  = (const float*)d_in[19];
    const float* bfuse  = (const float*)d_in[20];
    float* out = (float*)d_out;

    int N = in_sizes[0] / 2;   // x is (N,2)
    int E = in_sizes[1] / 2;   // edge_index is (2,E)
    int Etot = E + N;
    int EtotPad = (Etot + 511) & ~511;

    // workspace layout; zero region = meansum(0..4) + cnt
    size_t off = 0;
    float* meansum = (float*)((char*)d_ws + off);  off += 256;
    int*   cnt     = (int*)((char*)d_ws + off);    off += roundup256((size_t)N * sizeof(int));
    size_t zero_bytes = off;
    float* Lin     = (float*)((char*)d_ws + off);  off += 256;
    int*   cur     = (int*)((char*)d_ws + off);    off += roundup256((size_t)N * sizeof(int));
    int*   rowptr  = (int*)((char*)d_ws + off);    off += roundup256((size_t)(N + 1) * sizeof(int));
    float* packed  = (float*)((char*)d_ws + off);  off += roundup256(8 * 128 * 8 * sizeof(float));
    unsigned short* pwB = (unsigned short*)((char*)d_ws + off);
                                                   off += roundup256(4096 * 8 * sizeof(unsigned short));
    float4* ed4    = (float4*)((char*)d_ws + off); off += roundup256((size_t)EtotPad * sizeof(float4));
    float* ea1     = (float*)((char*)d_ws + off);  off += roundup256((size_t)EtotPad * sizeof(float));
    int*   esrc    = (int*)((char*)d_ws + off);    off += roundup256((size_t)EtotPad * sizeof(int));
    float* p8      = (float*)((char*)d_ws + off);  off += roundup256((size_t)EtotPad * 8 * sizeof(float));

    hipMemsetAsync(d_ws, 0, zero_bytes, stream);

    prep_kernel<<<(E + 255) / 256, 256, 0, stream>>>(
        ei, eattr, meansum, Lin, cnt,
        Wsrc0, bsrc0, Wdst0, bdst0, Wedge0, att0,
        Wsrc1, bsrc1, Wdst1, bdst1, Wedge1, att1,
        Wfuse, packed, pwB, E);

    scan_kernel<<<1, 1024, 0, stream>>>(cnt, rowptr, cur, N);

    scatter_kernel<<<(Etot + 255) / 256, 256, 0, stream>>>(
        ei, x, eattr, meansum, cur, ed4, ea1, esrc, N, E);

    int nchunks = EtotPad / 512;
    logits_kernel<<<4 * nchunks, 256, 0, stream>>>(
        ed4, ea1, Lin, (const float4*)packed, p8, EtotPad, nchunks);

    node_kernel<<<(N + NPB - 1) / NPB, 512, 0, stream>>>(
        x, rowptr, esrc, p8,
        Wsrc0, bsrc0, bias0, Wres0,
        Wsrc1, bsrc1, bias1, Wres1,
        pwB, bfuse, out, N, EtotPad);
}

// Round 22
// 158.831 us; speedup vs baseline: 1.0469x; 1.0469x over previous
//
#include <hip/hip_runtime.h>

#define HH 4
#define CC 128
#define NPB 64

typedef __attribute__((ext_vector_type(8))) short short8v;   // 8 bf16
typedef __attribute__((ext_vector_type(4))) float f32x4;

static inline size_t roundup256(size_t x) { return (x + 255) & ~(size_t)255; }

static __device__ __forceinline__ unsigned short f2bf(float f) {
    unsigned int u = __float_as_uint(f);
    unsigned int r = (u + 0x7FFFu + ((u >> 16) & 1u)) >> 16;   // RNE
    return (unsigned short)r;
}

// ---------------- prep: mean + hist + Lin + packed (f32) + pwB --------------
__global__ __launch_bounds__(256) void prep_kernel(
    const int* __restrict__ ei, const float* __restrict__ eattr,
    float* __restrict__ meansum, float* __restrict__ Lin, int* __restrict__ cnt,
    const float* __restrict__ Wsrc0, const float* __restrict__ bsrc0,
    const float* __restrict__ Wdst0, const float* __restrict__ bdst0,
    const float* __restrict__ Wedge0, const float* __restrict__ att0,
    const float* __restrict__ Wsrc1, const float* __restrict__ bsrc1,
    const float* __restrict__ Wdst1, const float* __restrict__ bdst1,
    const float* __restrict__ Wedge1, const float* __restrict__ att1,
    const float* __restrict__ Wfuse,
    float* __restrict__ packed, unsigned short* __restrict__ pwB, int E)
{
    int tid = blockIdx.x * 256 + threadIdx.x;
    int lane = threadIdx.x & 63, wid = threadIdx.x >> 6;
    float s = 0.f;
    if (tid < E) {
        atomicAdd(&cnt[ei[E + tid]], 1);
        s = eattr[tid];
    }
    #pragma unroll
    for (int off = 32; off > 0; off >>= 1) s += __shfl_down(s, off, 64);
    __shared__ float wsum[4];
    if (lane == 0) wsum[wid] = s;
    __syncthreads();
    if (threadIdx.x == 0)
        atomicAdd(meansum, wsum[0] + wsum[1] + wsum[2] + wsum[3]);

    if (blockIdx.x < 4) {  // tid < 1024: one thread per (b,h,c)
        int b = tid >> 9;
        int hc = tid & 511;
        int c = hc & 127;
        int h = hc >> 7;
        int bh = b * 4 + h;
        const float* Ws = b ? Wsrc1 : Wsrc0;
        const float* bs = b ? bsrc1 : bsrc0;
        const float* Wd = b ? Wdst1 : Wdst0;
        const float* bd = b ? bdst1 : bdst0;
        const float* We = b ? Wedge1 : Wedge0;
        const float* at = b ? att1 : att0;
        float A = Ws[hc], B = Ws[512 + hc];
        float C = Wd[hc], D = Wd[512 + hc];
        float Ec = We[hc];
        float F = bs[hc] + bd[hc];
        float a = at[hc];
        float4* r = (float4*)(packed + ((size_t)(bh * 128 + c)) * 8);
        r[0] = make_float4(A, B, C, D);
        r[1] = make_float4(Ec, F, 0.4f * a, 0.f);
        float sa = 0.6f * a;
        float vals[6] = {sa * A, sa * B, sa * C, sa * D, sa * Ec, sa * F};
        #pragma unroll
        for (int k = 0; k < 6; ++k) {
            float v = vals[k];
            #pragma unroll
            for (int off = 32; off > 0; off >>= 1) v += __shfl_down(v, off, 64);
            vals[k] = v;
        }
        __shared__ float Ls[4][6];
        if (lane == 0) {
            #pragma unroll
            for (int k = 0; k < 6; ++k) Ls[wid][k] = vals[k];
        }
        __syncthreads();
        if (threadIdx.x < 12) {
            int w2 = threadIdx.x / 6;
            int k = threadIdx.x % 6;
            int bhg = blockIdx.x * 2 + w2;
            Lin[bhg * 6 + k] = Ls[w2 * 2][k] + Ls[w2 * 2 + 1][k];
        }
    }

    if (blockIdx.x >= 4 && blockIdx.x < 20) {  // Wfuse -> bf16 B-frags (node)
        int t2 = tid - 1024;                   // 0..4095
        int ct = t2 >> 9;
        int kc = (t2 >> 6) & 7;
        int l  = t2 & 63;
        int c = ct * 16 + (l & 15);
        int kb = kc * 32 + (l >> 4) * 8;
        unsigned short v[8];
        #pragma unroll
        for (int j = 0; j < 8; ++j)
            v[j] = f2bf(Wfuse[(kb + j) * CC + c]);
        unsigned short* dst = pwB + (size_t)t2 * 8;
        #pragma unroll
        for (int j = 0; j < 8; ++j) dst[j] = v[j];
    }
}

// ---------------- scan: shuffle-based exclusive prefix over (cnt+1) ---------
__global__ __launch_bounds__(1024) void scan_kernel(const int* __restrict__ cnt,
                                                    int* __restrict__ rowptr,
                                                    int* __restrict__ cur, int N) {
    const int CH = 32;
    int t = threadIdx.x;
    int lane = t & 63, wid = t >> 6;
    int base = t * CH;
    int local[CH];
    int own = 0;
    #pragma unroll
    for (int i = 0; i < CH; ++i) {
        int idx = base + i;
        int v = (idx < N) ? cnt[idx] + 1 : 0;  // +1 = self loop
        local[i] = own;
        own += v;
    }
    int incl = own;
    #pragma unroll
    for (int off = 1; off < 64; off <<= 1) {
        int v = __shfl_up(incl, off, 64);
        if (lane >= off) incl += v;
    }
    __shared__ int wtot[16];
    __shared__ int wexcl[17];
    if (lane == 63) wtot[wid] = incl;
    __syncthreads();
    if (t == 0) {
        int acc = 0;
        #pragma unroll
        for (int w = 0; w < 16; ++w) { wexcl[w] = acc; acc += wtot[w]; }
        wexcl[16] = acc;
    }
    __syncthreads();
    int excl = wexcl[wid] + (incl - own);
    #pragma unroll
    for (int i = 0; i < CH; ++i) {
        int idx = base + i;
        if (idx < N) {
            int v = excl + local[i];
            rowptr[idx] = v;
            cur[idx] = v;
        }
    }
    if (t == 1023) rowptr[N] = wexcl[16];
}

// ---------------- scatter: CSR records ed4{xs,xd}, ea1, esrc ----------------
__global__ __launch_bounds__(256) void scatter_kernel(
    const int* __restrict__ ei, const float* __restrict__ x,
    const float* __restrict__ eattr, const float* __restrict__ meansum,
    int* __restrict__ cur, float4* __restrict__ ed4, float* __restrict__ ea1,
    int* __restrict__ esrc, int N, int E) {
    int e = blockIdx.x * 256 + threadIdx.x;
    int Etot = E + N;
    if (e >= Etot) return;
    int src, dst;
    float ea;
    if (e < E) { src = ei[e]; dst = ei[E + e]; ea = eattr[e]; }
    else       { src = e - E; dst = src; ea = meansum[0] / (float)E; }
    int pos = atomicAdd(&cur[dst], 1);
    const float2* x2 = (const float2*)x;
    float2 xs = x2[src];
    float2 xd = x2[dst];
    ed4[pos] = make_float4(xs.x, xs.y, xd.x, xd.y);
    ea1[pos] = ea;
    esrc[pos] = src;
}

// ---------------- logits: bh-split blocks, 4KB hot weight slice (R19) -------
// grid = 8 bh-phases x nchunks; each block: one bh, 512 edges (2/lane).
// logit_bh = Lin[bh].(xs0,xs1,xd0,xd1,ea,1) + sum_c G'_c * |u_c|
// p8 plane layout: p8[bh*EtotPad + i] = exp(logit_bh), coalesced stores.
__global__ __launch_bounds__(256) void logits_kernel(
    const float4* __restrict__ ed4,
    const float* __restrict__ ea1,
    const float* __restrict__ Lin,
    const float4* __restrict__ pw,   // (bh*128+c)*2 float4: {A,B,C,D},{E,F,G',0}
    float* __restrict__ p8, int EtotPad, int nchunks)
{
    int blk = blockIdx.x;
    int bh = blk / nchunks;          // phase-major: whole GPU sweeps one bh
    int chunk = blk - bh * nchunks;
    int t = threadIdx.x;
    int iA = chunk * 512 + t;
    int iB = iA + 256;
    float4 eA = ed4[iA], eB = ed4[iB];
    float aA = ea1[iA], aB = ea1[iB];

    const float4* wp = pw + (size_t)bh * 256;   // 4KB slice, scalar-L1 hot
    float a0 = 0.f, a1 = 0.f;
    #pragma unroll 8
    for (int c = 0; c < 128; ++c) {
        float4 w0 = wp[2 * c];       // uniform -> s_load, K$ hit
        float4 w1 = wp[2 * c + 1];
        float uA = fmaf(w0.x, eA.x,
                   fmaf(w0.y, eA.y,
                   fmaf(w0.z, eA.z,
                   fmaf(w0.w, eA.w,
                   fmaf(w1.x, aA, w1.y)))));
        float uB = fmaf(w0.x, eB.x,
                   fmaf(w0.y, eB.y,
                   fmaf(w0.z, eB.z,
                   fmaf(w0.w, eB.w,
                   fmaf(w1.x, aB, w1.y)))));
        a0 = fmaf(w1.z, __builtin_fabsf(uA), a0);  // |u| = free src modifier
        a1 = fmaf(w1.z, __builtin_fabsf(uB), a1);
    }

    const float* Lp = Lin + bh * 6;   // uniform -> s_load
    float lgA = fmaf(Lp[0], eA.x, fmaf(Lp[1], eA.y, fmaf(Lp[2], eA.z,
                fmaf(Lp[3], eA.w, fmaf(Lp[4], aA, Lp[5]))))) + a0;
    float lgB = fmaf(Lp[0], eB.x, fmaf(Lp[1], eB.y, fmaf(Lp[2], eB.z,
                fmaf(Lp[3], eB.w, fmaf(Lp[4], aB, Lp[5]))))) + a1;
    float* plane = p8 + (size_t)bh * EtotPad;
    plane[iA] = __expf(lgA);
    plane[iB] = __expf(lgB);
}

// ---------------- node: gather (fused) + h-build + MFMA fuse GEMM -----------
// phase0: 16 lanes/node (8 bh x 2 edge-parity), shfl_xor(8) combine, 2 passes
__global__ __launch_bounds__(512) void node_kernel(
    const float* __restrict__ x,
    const int* __restrict__ rowptr,
    const int* __restrict__ esrc,
    const float* __restrict__ p8,
    const float* __restrict__ Wsrc0, const float* __restrict__ bsrc0,
    const float* __restrict__ bias0, const float* __restrict__ Wres0,
    const float* __restrict__ Wsrc1, const float* __restrict__ bsrc1,
    const float* __restrict__ bias1, const float* __restrict__ Wres1,
    const unsigned short* __restrict__ pwB, const float* __restrict__ bfuse,
    float* __restrict__ out, int N, int EtotPad)
{
    __shared__ __align__(16) unsigned short hb[NPB][264];  // 33 KB
    __shared__ __align__(16) float Sl[NPB][24];            // 6 KB
    int t = threadIdx.x;
    int n0 = blockIdx.x * NPB;
    const float2* x2 = (const float2*)x;

    // ---- phase 0: per-node gather, 16 lanes/node, two passes ----
    {
        int g = t >> 4;            // 0..31 node in pass
        int sub = t & 15;
        int bh = sub & 7;
        int half = sub >> 3;       // edge parity
        const float* plane = p8 + (size_t)bh * EtotPad;
        #pragma unroll
        for (int pass = 0; pass < 2; ++pass) {
            int ni = g + pass * 32;
            int n = n0 + ni;
            if (n < N) {
                int beg = rowptr[n], end = rowptr[n + 1];
                float s0 = 0.f, s1 = 0.f, sb = 0.f;
                for (int i = beg + half; i < end; i += 2) {
                    float p = plane[i];
                    int srcu = esrc[i];
                    float2 xs = x2[srcu];       // L2-hot gather
                    s0 = fmaf(p, xs.x, s0);
                    s1 = fmaf(p, xs.y, s1);
                    sb += p;
                }
                s0 += __shfl_xor(s0, 8, 64);
                s1 += __shfl_xor(s1, 8, 64);
                sb += __shfl_xor(sb, 8, 64);
                if (half == 0) {
                    float rin = 1.f / (sb + 1e-16f);
                    Sl[ni][bh * 3 + 0] = s0 * rin;
                    Sl[ni][bh * 3 + 1] = s1 * rin;
                    Sl[ni][bh * 3 + 2] = sb * rin;
                }
            }
        }
    }
    __syncthreads();

    // ---- phase 1: h build ----
    int c = t & (CC - 1);
    int quarter = t >> 7;

    float w00[HH], w01[HH], wb0[HH], w10[HH], w11[HH], wb1[HH];
    #pragma unroll
    for (int h = 0; h < HH; ++h) {
        w00[h] = Wsrc0[h * CC + c];
        w01[h] = Wsrc0[512 + h * CC + c];
        wb0[h] = bsrc0[h * CC + c];
        w10[h] = Wsrc1[h * CC + c];
        w11[h] = Wsrc1[512 + h * CC + c];
        wb1[h] = bsrc1[h * CC + c];
    }
    float bi0 = bias0[c], bi1 = bias1[c];
    float r00 = Wres0[c], r01 = Wres0[CC + c];
    float r10 = Wres1[c], r11 = Wres1[CC + c];

    for (int ni = quarter; ni < NPB; ni += 4) {
        int n = n0 + ni;
        if (n < N) {
            float x0 = x[2 * n], x1 = x[2 * n + 1];
            const float4* Sp4 = (const float4*)&Sl[ni][0];  // LDS broadcast
            float4 q0 = Sp4[0], q1 = Sp4[1], q2 = Sp4[2];
            float4 q3 = Sp4[3], q4 = Sp4[4], q5 = Sp4[5];
            float h0v, h1v;
            {
                float s0[HH] = {q0.x, q0.w, q1.z, q2.y};
                float s1[HH] = {q0.y, q1.x, q1.w, q2.z};
                float sb[HH] = {q0.z, q1.y, q2.x, q2.w};
                float acc = 0.f;
                #pragma unroll
                for (int h = 0; h < HH; ++h)
                    acc += fmaf(w00[h], s0[h], fmaf(w01[h], s1[h], wb0[h] * sb[h]));
                float o = fmaxf(acc * 0.25f + bi0, 0.f);
                h0v = o + x0 * r00 + x1 * r01;
            }
            {
                float s0[HH] = {q3.x, q3.w, q4.z, q5.y};
                float s1[HH] = {q3.y, q4.x, q4.w, q5.z};
                float sb[HH] = {q3.z, q4.y, q5.x, q5.w};
                float acc = 0.f;
                #pragma unroll
                for (int h = 0; h < HH; ++h)
                    acc += fmaf(w10[h], s0[h], fmaf(w11[h], s1[h], wb1[h] * sb[h]));
                float o = fmaxf(acc * 0.25f + bi1, 0.f);
                h1v = o + x0 * r10 + x1 * r11;
            }
            hb[ni][c] = f2bf(h0v);
            hb[ni][CC + c] = f2bf(h1v);
        }
    }
    __syncthreads();

    // ---- phase 2: MFMA ----
    int w = t >> 6;
    int l = t & 63;
    int nt = w & 3;
    int cthalf = w >> 2;
    int row = nt * 16 + (l & 15);

    short8v a[8];
    #pragma unroll
    for (int kc = 0; kc < 8; ++kc)
        a[kc] = *reinterpret_cast<const short8v*>(&hb[row][kc * 32 + (l >> 4) * 8]);

    const short8v* pB = reinterpret_cast<const short8v*>(pwB);
    #pragma unroll
    for (int ci = 0; ci < 4; ++ci) {
        int ct = cthalf * 4 + ci;
        f32x4 acc = {0.f, 0.f, 0.f, 0.f};
        #pragma unroll
        for (int kc = 0; kc < 8; ++kc) {
            short8v b = pB[(ct * 8 + kc) * 64 + l];
            acc = __builtin_amdgcn_mfma_f32_16x16x32_bf16(a[kc], b, acc, 0, 0, 0);
        }
        int ch = ct * 16 + (l & 15);
        float bi = bfuse[ch];
        #pragma unroll
        for (int j = 0; j < 4; ++j) {
            int n = n0 + nt * 16 + (l >> 4) * 4 + j;
            if (n < N) out[(size_t)n * CC + ch] = fmaxf(acc[j] + bi, 0.f);
        }
    }
}

extern "C" void kernel_launch(void* const* d_in, const int* in_sizes, int n_in,
                              void* d_out, int out_size, void* d_ws, size_t ws_size,
                              hipStream_t stream) {
    const float* x      = (const float*)d_in[0];
    const int*   ei     = (const int*)d_in[1];
    const float* eattr  = (const float*)d_in[2];
    const float* Wsrc0  = (const float*)d_in[3];
    const float* bsrc0  = (const float*)d_in[4];
    const float* Wdst0  = (const float*)d_in[5];
    const float* bdst0  = (const float*)d_in[6];
    const float* Wedge0 = (const float*)d_in[7];
    const float* att0   = (const float*)d_in[8];
    const float* bias0  = (const float*)d_in[9];
    const float* Wres0  = (const float*)d_in[10];
    const float* Wsrc1  = (const float*)d_in[11];
    const float* bsrc1  = (const float*)d_in[12];
    const float* Wdst1  = (const float*)d_in[13];
    const float* bdst1  = (const float*)d_in[14];
    const float* Wedge1 = (const float*)d_in[15];
    const float* att1   = (const float*)d_in[16];
    const float* bias1  = (const float*)d_in[17];
    const float* Wres1  = (const float*)d_in[18];
    const float* Wfuse  = (const float*)d_in[19];
    const float* bfuse  = (const float*)d_in[20];
    float* out = (float*)d_out;

    int N = in_sizes[0] / 2;   // x is (N,2)
    int E = in_sizes[1] / 2;   // edge_index is (2,E)
    int Etot = E + N;
    int EtotPad = (Etot + 511) & ~511;

    // workspace layout; zero region = meansum(0..4) + cnt
    size_t off = 0;
    float* meansum = (float*)((char*)d_ws + off);  off += 256;
    int*   cnt     = (int*)((char*)d_ws + off);    off += roundup256((size_t)N * sizeof(int));
    size_t zero_bytes = off;
    float* Lin     = (float*)((char*)d_ws + off);  off += 256;
    int*   cur     = (int*)((char*)d_ws + off);    off += roundup256((size_t)N * sizeof(int));
    int*   rowptr  = (int*)((char*)d_ws + off);    off += roundup256((size_t)(N + 1) * sizeof(int));
    float* packed  = (float*)((char*)d_ws + off);  off += roundup256(8 * 128 * 8 * sizeof(float));
    unsigned short* pwB = (unsigned short*)((char*)d_ws + off);
                                                   off += roundup256(4096 * 8 * sizeof(unsigned short));
    float4* ed4    = (float4*)((char*)d_ws + off); off += roundup256((size_t)EtotPad * sizeof(float4));
    float* ea1     = (float*)((char*)d_ws + off);  off += roundup256((size_t)EtotPad * sizeof(float));
    int*   esrc    = (int*)((char*)d_ws + off);    off += roundup256((size_t)EtotPad * sizeof(int));
    float* p8      = (float*)((char*)d_ws + off);  off += roundup256((size_t)EtotPad * 8 * sizeof(float));

    hipMemsetAsync(d_ws, 0, zero_bytes, stream);

    prep_kernel<<<(E + 255) / 256, 256, 0, stream>>>(
        ei, eattr, meansum, Lin, cnt,
        Wsrc0, bsrc0, Wdst0, bdst0, Wedge0, att0,
        Wsrc1, bsrc1, Wdst1, bdst1, Wedge1, att1,
        Wfuse, packed, pwB, E);

    scan_kernel<<<1, 1024, 0, stream>>>(cnt, rowptr, cur, N);

    scatter_kernel<<<(Etot + 255) / 256, 256, 0, stream>>>(
        ei, x, eattr, meansum, cur, ed4, ea1, esrc, N, E);

    int nchunks = EtotPad / 512;
    logits_kernel<<<8 * nchunks, 256, 0, stream>>>(
        ed4, ea1, Lin, (const float4*)packed, p8, EtotPad, nchunks);

    node_kernel<<<(N + NPB - 1) / NPB, 512, 0, stream>>>(
        x, rowptr, esrc, p8,
        Wsrc0, bsrc0, bias0, Wres0,
        Wsrc1, bsrc1, bias1, Wres1,
        pwB, bfuse, out, N, EtotPad);
}